// Round 1
// baseline (1807.743 us; speedup 1.0000x reference)
//
#include <hip/hip_runtime.h>
#include <cstdio>

#define B_   256
#define H_   512
#define G4_  2048
#define T_   326
#define OUT_ 9

typedef __attribute__((ext_vector_type(8))) short s16x8;
typedef __attribute__((ext_vector_type(4))) float f32x4;

__device__ inline unsigned short to_bf16(float f) {
    unsigned int u = __builtin_bit_cast(unsigned int, f);
    unsigned int r = (u + 0x7fffu + ((u >> 16) & 1u)) >> 16;  // RNE
    return (unsigned short)r;
}

__device__ inline float sigmoidf_(float x) { return 1.0f / (1.0f + __expf(-x)); }

__device__ inline float fast_tanh(float x) {
    x = fminf(fmaxf(x, -15.f), 15.f);
    float e = __expf(2.f * x);
    return (e - 1.f) / (e + 1.f);
}

// ---------------- prep kernels ----------------

__global__ void prep_weights(const float* __restrict__ Wih, const float* __restrict__ Whh,
                             const float* __restrict__ bih, const float* __restrict__ bhh,
                             unsigned short* __restrict__ Wc, unsigned short* __restrict__ Wcat,
                             float* __restrict__ bc) {
    int idx = blockIdx.x * 256 + threadIdx.x;      // < 2048*512
    int n = idx >> 9, k = idx & 511;
    float wi = Wih[idx], wh = Whh[idx];
    Wc[idx] = to_bf16(wi + wh);
    Wcat[(n << 10) + k]       = to_bf16(wi);
    Wcat[(n << 10) + 512 + k] = to_bf16(wh);
    if (k == 0) bc[n] = bih[n] + bhh[n];
}

__global__ void prep_w1(const float* __restrict__ W1, unsigned short* __restrict__ W1b) {
    int idx = blockIdx.x * 256 + threadIdx.x;      // < 512*512
    W1b[idx] = to_bf16(W1[idx]);
}

__global__ void prep_w2(const float* __restrict__ W2, unsigned short* __restrict__ W2b) {
    int idx = blockIdx.x * 256 + threadIdx.x;      // < 16*512
    int o = idx >> 9, k = idx & 511;
    W2b[idx] = (o < OUT_) ? to_bf16(W2[o * H_ + k]) : (unsigned short)0;
}

__global__ void prep_x(const float* __restrict__ x, const float* __restrict__ hx0,
                       unsigned short* __restrict__ xcat) {
    int idx = blockIdx.x * 256 + threadIdx.x;      // < 256*512
    int b = idx >> 9, k = idx & 511;
    xcat[(b << 10) + k]       = to_bf16(x[idx]);
    xcat[(b << 10) + 512 + k] = to_bf16(hx0[idx]);
}

// ---------------- step 0 (K=1024, [x|hx0] @ [Wih|Whh]) ----------------
template <int KLEN>
__global__ __launch_bounds__(256) void lstm_step(
    const unsigned short* __restrict__ A,
    const unsigned short* __restrict__ W,
    const float* __restrict__ bc,
    const float* __restrict__ c_in,
    float* __restrict__ c_out,
    unsigned short* __restrict__ h_out) {
    const int lane = threadIdx.x & 63;
    const int wave = threadIdx.x >> 6;
    const int mn = lane & 15, q = lane >> 4;
    const int rt = blockIdx.x & 15;
    const int hb = (blockIdx.x >> 4) * 64 + wave * 16;

    const unsigned short* ap  = A + (size_t)(rt * 16 + mn) * KLEN + q * 8;
    const unsigned short* wp0 = W + (size_t)(0 * H_ + hb + mn) * KLEN + q * 8;
    const unsigned short* wp1 = W + (size_t)(1 * H_ + hb + mn) * KLEN + q * 8;
    const unsigned short* wp2 = W + (size_t)(2 * H_ + hb + mn) * KLEN + q * 8;
    const unsigned short* wp3 = W + (size_t)(3 * H_ + hb + mn) * KLEN + q * 8;

    f32x4 acc0 = {0.f,0.f,0.f,0.f}, acc1 = {0.f,0.f,0.f,0.f};
    f32x4 acc2 = {0.f,0.f,0.f,0.f}, acc3 = {0.f,0.f,0.f,0.f};
#pragma unroll 4
    for (int k0 = 0; k0 < KLEN; k0 += 32) {
        s16x8 a  = *reinterpret_cast<const s16x8*>(ap + k0);
        s16x8 w0 = *reinterpret_cast<const s16x8*>(wp0 + k0);
        s16x8 w1 = *reinterpret_cast<const s16x8*>(wp1 + k0);
        s16x8 w2 = *reinterpret_cast<const s16x8*>(wp2 + k0);
        s16x8 w3 = *reinterpret_cast<const s16x8*>(wp3 + k0);
        acc0 = __builtin_amdgcn_mfma_f32_16x16x32_bf16(a, w0, acc0, 0, 0, 0);
        acc1 = __builtin_amdgcn_mfma_f32_16x16x32_bf16(a, w1, acc1, 0, 0, 0);
        acc2 = __builtin_amdgcn_mfma_f32_16x16x32_bf16(a, w2, acc2, 0, 0, 0);
        acc3 = __builtin_amdgcn_mfma_f32_16x16x32_bf16(a, w3, acc3, 0, 0, 0);
    }

    const int j = hb + mn;
    const float bi = bc[j], bfv = bc[H_ + j], bg = bc[2 * H_ + j], bo = bc[3 * H_ + j];
#pragma unroll
    for (int r = 0; r < 4; ++r) {
        const int row = rt * 16 + q * 4 + r;
        const float iv = sigmoidf_(acc0[r] + bi);
        const float fv = sigmoidf_(acc1[r] + bfv);
        const float gv = fast_tanh(acc2[r] + bg);
        const float ov = sigmoidf_(acc3[r] + bo);
        const float co = c_in[row * H_ + j];
        const float cn = fv * co + iv * gv;
        c_out[row * H_ + j] = cn;
        h_out[row * H_ + j] = to_bf16(ov * fast_tanh(cn));
    }
}

// ---------------- persistent LSTM (steps 1..325) ----------------
// 256 WGs x 256 thr (cooperative). 8 INDEPENDENT groups: mt = blockIdx&7 owns
// rows [mt*32, mt*32+32); p = blockIdx>>3 owns hidden cols [16p, 16p+16).
// Dataflow sync (NO group barrier): per step each producer WG publishes a
// per-producer flag (= step id) after its h-store drains (__syncthreads emits
// vmcnt(0)). Consumers spin on min(flags of a 128-col quarter) >= t-1, then
// load that quarter; loads of quarter k overlap the spin of quarter k+1, and
// WGs may skew arbitrarily (flags monotonic, h_hist has one slot per step).
// All data ops sc1 (relaxed AGENT atomics) relying on same-XCD L2, identical
// to the verified barrier version. No __threadfence / release atomics.
__global__ __launch_bounds__(256) void lstm_persist(
    const unsigned short* __restrict__ Wc,   // [2048][512] bf16
    const float* __restrict__ bc,            // [2048]
    const float* __restrict__ c0,            // [256][512] f32 (from step 0)
    unsigned short* __restrict__ h_hist,     // [326][256][512] bf16
    unsigned int* __restrict__ flg) {        // 32 quarter-lines x 128B; 8 flags each
    constexpr int AS = 520;                      // ushort stride (pad 8)
    __shared__ unsigned short A_lds[32 * AS];    // 33280 B
    __shared__ float gate_lds[4 * 32 * 17];      // 8704 B
    const int tid = threadIdx.x;
    const int lane = tid & 63, wave = tid >> 6;
    const int mn = lane & 15, q = lane >> 4;
    const int mt = blockIdx.x & 7;               // group = likely same XCD
    const int p  = blockIdx.x >> 3;              // col chunk 0..31
    const int jb = p * 16;
    // flag layout: line (mt*4 + quarter) holds flags of its 8 producers
    unsigned int* my_flag = flg + (mt * 4 + (p >> 3)) * 32 + (p & 7);

    // weights -> registers (B-fragment layout: n=mn, k=kk*32+q*8)
    s16x8 breg[16];
    {
        const unsigned short* wp = Wc + (size_t)(wave * H_ + jb + mn) * H_ + q * 8;
#pragma unroll
        for (int kk = 0; kk < 16; ++kk) breg[kk] = *reinterpret_cast<const s16x8*>(wp + kk * 32);
    }
    const float bcv = bc[wave * H_ + jb + mn];

    // owned c/h elements: row = tid>>3 (0..31), cols c0..c0+1 (c0 = 2*(tid&7))
    const int crow = tid >> 3, cc0 = (tid & 7) * 2;
    float c_x = c0[(size_t)(mt * 32 + crow) * H_ + jb + cc0];
    float c_y = c0[(size_t)(mt * 32 + crow) * H_ + jb + cc0 + 1];

    // A staging ownership: row arow (0..31), qword cols aw..aw+4 per quarter
    const int arow = tid >> 3;
    const int aw   = (tid & 7) * 4;

    for (int t = 1; t < T_; ++t) {
        const unsigned long long* hsrc64 = reinterpret_cast<const unsigned long long*>(
            h_hist + (size_t)(t - 1) * (B_ * H_) + (size_t)mt * 32 * H_);
        const unsigned int tgt = (unsigned int)(t - 1);
        unsigned long long vv[16];
#pragma unroll
        for (int kb = 0; kb < 4; ++kb) {
            // ---- wait for the 8 producers of cols [128*kb, 128*kb+128) ----
            const unsigned long long* f64 = reinterpret_cast<const unsigned long long*>(
                flg + (mt * 4 + kb) * 32);
            for (;;) {
                unsigned long long f0 = __hip_atomic_load(f64 + 0, __ATOMIC_RELAXED, __HIP_MEMORY_SCOPE_AGENT);
                unsigned long long f1 = __hip_atomic_load(f64 + 1, __ATOMIC_RELAXED, __HIP_MEMORY_SCOPE_AGENT);
                unsigned long long f2 = __hip_atomic_load(f64 + 2, __ATOMIC_RELAXED, __HIP_MEMORY_SCOPE_AGENT);
                unsigned long long f3 = __hip_atomic_load(f64 + 3, __ATOMIC_RELAXED, __HIP_MEMORY_SCOPE_AGENT);
                unsigned int m0 = min((unsigned int)f0, (unsigned int)(f0 >> 32));
                unsigned int m1 = min((unsigned int)f1, (unsigned int)(f1 >> 32));
                unsigned int m2 = min((unsigned int)f2, (unsigned int)(f2 >> 32));
                unsigned int m3 = min((unsigned int)f3, (unsigned int)(f3 >> 32));
                if (min(min(m0, m1), min(m2, m3)) >= tgt) break;
            }
            asm volatile("" ::: "memory");   // keep data loads after the spin
            // ---- issue this quarter's loads (overlap next quarter's spin) ----
            const unsigned long long* src = hsrc64 + (size_t)arow * 128 + kb * 32 + aw;
#pragma unroll
            for (int j = 0; j < 4; ++j)
                vv[kb * 4 + j] = __hip_atomic_load(src + j, __ATOMIC_RELAXED,
                                                   __HIP_MEMORY_SCOPE_AGENT);
        }
#pragma unroll
        for (int kb = 0; kb < 4; ++kb)
#pragma unroll
            for (int j = 0; j < 4; ++j)
                *reinterpret_cast<unsigned long long*>(
                    &A_lds[arow * AS + (kb * 32 + aw + j) * 4]) = vv[kb * 4 + j];
        __syncthreads();

        // ---- gates via MFMA (M=32 as 2 subtiles, N=16, K=512) ----
        f32x4 acc0 = {0.f,0.f,0.f,0.f}, acc1 = {0.f,0.f,0.f,0.f};
#pragma unroll
        for (int kk = 0; kk < 16; ++kk) {
            s16x8 a0 = *reinterpret_cast<const s16x8*>(&A_lds[mn * AS + kk * 32 + q * 8]);
            s16x8 a1 = *reinterpret_cast<const s16x8*>(&A_lds[(16 + mn) * AS + kk * 32 + q * 8]);
            acc0 = __builtin_amdgcn_mfma_f32_16x16x32_bf16(a0, breg[kk], acc0, 0, 0, 0);
            acc1 = __builtin_amdgcn_mfma_f32_16x16x32_bf16(a1, breg[kk], acc1, 0, 0, 0);
        }

        // ---- activations -> gate LDS (C-layout: col=mn, row=q*4+r) ----
#pragma unroll
        for (int r = 0; r < 4; ++r) {
            float v0 = acc0[r] + bcv, v1 = acc1[r] + bcv;
            if (wave == 2) { v0 = fast_tanh(v0); v1 = fast_tanh(v1); }
            else           { v0 = sigmoidf_(v0); v1 = sigmoidf_(v1); }
            gate_lds[(wave * 32 + (q * 4 + r)) * 17 + mn]      = v0;
            gate_lds[(wave * 32 + (16 + q * 4 + r)) * 17 + mn] = v1;
        }
        __syncthreads();

        // ---- c/h update (2 adjacent cols of one row per thread) ----
        {
            float iv0 = gate_lds[(0 * 32 + crow) * 17 + cc0], iv1 = gate_lds[(0 * 32 + crow) * 17 + cc0 + 1];
            float fv0 = gate_lds[(1 * 32 + crow) * 17 + cc0], fv1 = gate_lds[(1 * 32 + crow) * 17 + cc0 + 1];
            float gv0 = gate_lds[(2 * 32 + crow) * 17 + cc0], gv1 = gate_lds[(2 * 32 + crow) * 17 + cc0 + 1];
            float ov0 = gate_lds[(3 * 32 + crow) * 17 + cc0], ov1 = gate_lds[(3 * 32 + crow) * 17 + cc0 + 1];
            c_x = fv0 * c_x + iv0 * gv0;
            c_y = fv1 * c_y + iv1 * gv1;
            unsigned int h0 = to_bf16(ov0 * fast_tanh(c_x));
            unsigned int h1 = to_bf16(ov1 * fast_tanh(c_y));
            unsigned int packed = h0 | (h1 << 16);
            unsigned int* hdst = reinterpret_cast<unsigned int*>(
                h_hist + (size_t)t * (B_ * H_) + (size_t)(mt * 32 + crow) * H_ + jb + cc0);
            __hip_atomic_store(hdst, packed, __ATOMIC_RELAXED, __HIP_MEMORY_SCOPE_AGENT);
        }

        // ---- publish: drain h-stores (vmcnt(0) inside __syncthreads), set flag ----
        if (t < T_ - 1) {
            __syncthreads();  // all 256 threads' sc1 h-stores complete in L2
            asm volatile("" ::: "memory");
            if (tid == 0)
                __hip_atomic_store(my_flag, (unsigned int)t, __ATOMIC_RELAXED,
                                   __HIP_MEMORY_SCOPE_AGENT);
        }
    }
}

// ---------------- deferred MLP head ----------------
__global__ __launch_bounds__(256) void mlp_kernel(
    const unsigned short* __restrict__ h_hist,
    const unsigned short* __restrict__ W1b,
    const float* __restrict__ b1,
    const unsigned short* __restrict__ W2b,
    const float* __restrict__ b2,
    float* __restrict__ out) {
    constexpr int ZS = 520;
    __shared__ unsigned short z_lds[32 * ZS];

    const int lane = threadIdx.x & 63;
    const int wave = threadIdx.x >> 6;
    const int mn = lane & 15, q = lane >> 4;
    const int t = blockIdx.x >> 2, mt = blockIdx.x & 3;

    const unsigned short* Abase = h_hist + ((size_t)t * B_ + mt * 64) * H_;
    const int nb = wave * 128;

    f32x4 zero4 = {0.f,0.f,0.f,0.f};
    f32x4 acc[4][8];
#pragma unroll
    for (int m4 = 0; m4 < 4; ++m4)
#pragma unroll
        for (int nt = 0; nt < 8; ++nt) acc[m4][nt] = zero4;

    for (int k0 = 0; k0 < 512; k0 += 32) {
        s16x8 a[4];
#pragma unroll
        for (int m4 = 0; m4 < 4; ++m4)
            a[m4] = *reinterpret_cast<const s16x8*>(Abase + (size_t)(m4 * 16 + mn) * H_ + k0 + q * 8);
#pragma unroll
        for (int nt = 0; nt < 8; ++nt) {
            s16x8 b = *reinterpret_cast<const s16x8*>(W1b + (size_t)(nb + nt * 16 + mn) * H_ + k0 + q * 8);
#pragma unroll
            for (int m4 = 0; m4 < 4; ++m4)
                acc[m4][nt] = __builtin_amdgcn_mfma_f32_16x16x32_bf16(a[m4], b, acc[m4][nt], 0, 0, 0);
        }
    }

    float b1v[8];
#pragma unroll
    for (int nt = 0; nt < 8; ++nt) b1v[nt] = b1[nb + nt * 16 + mn];

    for (int pass = 0; pass < 2; ++pass) {
        __syncthreads();
#pragma unroll
        for (int m4i = 0; m4i < 2; ++m4i) {
            const int m4 = 2 * pass + m4i;
            const int rl = m4i * 16 + q * 4;
#pragma unroll
            for (int nt = 0; nt < 8; ++nt) {
                const int col = nb + nt * 16 + mn;
#pragma unroll
                for (int r = 0; r < 4; ++r) {
                    float v = acc[m4][nt][r] + b1v[nt];
                    v = v > 0.f ? v : 0.f;
                    z_lds[(rl + r) * ZS + col] = to_bf16(v);
                }
            }
        }
        __syncthreads();
        if (wave < 2) {
            f32x4 yacc = {0.f,0.f,0.f,0.f};
#pragma unroll 4
            for (int k0 = 0; k0 < 512; k0 += 32) {
                s16x8 az = *reinterpret_cast<const s16x8*>(&z_lds[(wave * 16 + mn) * ZS + k0 + q * 8]);
                s16x8 bw = *reinterpret_cast<const s16x8*>(W2b + (size_t)mn * H_ + k0 + q * 8);
                yacc = __builtin_amdgcn_mfma_f32_16x16x32_bf16(az, bw, yacc, 0, 0, 0);
            }
            if (mn < OUT_) {
                const float bias = b2[mn];
#pragma unroll
                for (int r = 0; r < 4; ++r) {
                    const int row_local = pass * 32 + wave * 16 + q * 4 + r;
                    const int b = mt * 64 + row_local;
                    out[(size_t)b * (T_ * OUT_) + t * OUT_ + mn] = yacc[r] + bias;
                }
            }
        }
    }
}

// ---------------- host launch ----------------
extern "C" void kernel_launch(void* const* d_in, const int* in_sizes, int n_in,
                              void* d_out, int out_size, void* d_ws, size_t ws_size,
                              hipStream_t stream) {
    (void)in_sizes; (void)n_in; (void)out_size;
    const float* x   = (const float*)d_in[0];
    const float* hx0 = (const float*)d_in[1];
    const float* cx0 = (const float*)d_in[2];
    const float* Wih = (const float*)d_in[3];
    const float* Whh = (const float*)d_in[4];
    const float* bih = (const float*)d_in[5];
    const float* bhh = (const float*)d_in[6];
    const float* W1  = (const float*)d_in[7];
    const float* b1  = (const float*)d_in[8];
    const float* W2  = (const float*)d_in[9];
    const float* b2  = (const float*)d_in[10];
    float* out = (float*)d_out;

    char* p = (char*)d_ws;
    size_t off = 0;
    auto alloc = [&](size_t bytes) {
        void* r = p + off;
        off = (off + bytes + 255) & ~(size_t)255;
        return r;
    };
    unsigned short* Wc     = (unsigned short*)alloc((size_t)G4_ * H_ * 2);
    unsigned short* Wcat   = (unsigned short*)alloc((size_t)G4_ * 1024 * 2);
    unsigned short* W1b    = (unsigned short*)alloc((size_t)H_ * H_ * 2);
    unsigned short* W2b    = (unsigned short*)alloc((size_t)16 * H_ * 2);
    float*          bc     = (float*)alloc((size_t)G4_ * 4);
    unsigned short* xcat   = (unsigned short*)alloc((size_t)B_ * 1024 * 2);
    float*          cbuf   = (float*)alloc((size_t)B_ * H_ * 4);
    unsigned int*   flg    = (unsigned int*)alloc(4096);
    unsigned short* h_hist = (unsigned short*)alloc((size_t)T_ * B_ * H_ * 2);
    if (off > ws_size) {
        fprintf(stderr, "kernel_launch: ws too small: need %zu have %zu\n", off, ws_size);
        return;
    }

    prep_weights<<<G4_ * H_ / 256, 256, 0, stream>>>(Wih, Whh, bih, bhh, Wc, Wcat, bc);
    prep_w1<<<H_ * H_ / 256, 256, 0, stream>>>(W1, W1b);
    prep_w2<<<16 * H_ / 256, 256, 0, stream>>>(W2, W2b);
    prep_x<<<B_ * H_ / 256, 256, 0, stream>>>(x, hx0, xcat);

    // step 0: K=1024
    lstm_step<1024><<<128, 256, 0, stream>>>(xcat, Wcat, bc, cx0, cbuf, h_hist);

    // zero producer flags (flag==0 means "step 0 ready"), then persistent steps 1..325
    hipMemsetAsync(flg, 0, 4096, stream);
    {
        const unsigned short* Wc_l = Wc;
        const float* bc_l = bc;
        const float* c0_l = cbuf;
        unsigned short* hh_l = h_hist;
        unsigned int* flg_l = flg;
        void* args[5] = {(void*)&Wc_l, (void*)&bc_l, (void*)&c0_l, (void*)&hh_l, (void*)&flg_l};
        hipLaunchCooperativeKernel((const void*)lstm_persist, dim3(256), dim3(256), args, 0, stream);
    }

    mlp_kernel<<<T_ * 4, 256, 0, stream>>>(h_hist, W1b, b1, W2b, b2, out);
}

// Round 2
// 1522.009 us; speedup vs baseline: 1.1877x; 1.1877x over previous
//
#include <hip/hip_runtime.h>
#include <cstdio>

#define B_   256
#define H_   512
#define G4_  2048
#define T_   326
#define OUT_ 9

typedef __attribute__((ext_vector_type(8))) short s16x8;
typedef __attribute__((ext_vector_type(4))) float f32x4;

__device__ inline unsigned short to_bf16(float f) {
    unsigned int u = __builtin_bit_cast(unsigned int, f);
    unsigned int r = (u + 0x7fffu + ((u >> 16) & 1u)) >> 16;  // RNE
    return (unsigned short)r;
}

__device__ inline float sigmoidf_(float x) { return 1.0f / (1.0f + __expf(-x)); }

__device__ inline float fast_tanh(float x) {
    x = fminf(fmaxf(x, -15.f), 15.f);
    float e = __expf(2.f * x);
    return (e - 1.f) / (e + 1.f);
}

// ---------------- prep kernels ----------------

__global__ void prep_weights(const float* __restrict__ Wih, const float* __restrict__ Whh,
                             const float* __restrict__ bih, const float* __restrict__ bhh,
                             unsigned short* __restrict__ Wc, unsigned short* __restrict__ Wcat,
                             float* __restrict__ bc) {
    int idx = blockIdx.x * 256 + threadIdx.x;      // < 2048*512
    int n = idx >> 9, k = idx & 511;
    float wi = Wih[idx], wh = Whh[idx];
    Wc[idx] = to_bf16(wi + wh);
    Wcat[(n << 10) + k]       = to_bf16(wi);
    Wcat[(n << 10) + 512 + k] = to_bf16(wh);
    if (k == 0) bc[n] = bih[n] + bhh[n];
}

__global__ void prep_w1(const float* __restrict__ W1, unsigned short* __restrict__ W1b) {
    int idx = blockIdx.x * 256 + threadIdx.x;      // < 512*512
    W1b[idx] = to_bf16(W1[idx]);
}

__global__ void prep_w2(const float* __restrict__ W2, unsigned short* __restrict__ W2b) {
    int idx = blockIdx.x * 256 + threadIdx.x;      // < 16*512
    int o = idx >> 9, k = idx & 511;
    W2b[idx] = (o < OUT_) ? to_bf16(W2[o * H_ + k]) : (unsigned short)0;
}

__global__ void prep_x(const float* __restrict__ x, const float* __restrict__ hx0,
                       unsigned short* __restrict__ xcat) {
    int idx = blockIdx.x * 256 + threadIdx.x;      // < 256*512
    int b = idx >> 9, k = idx & 511;
    xcat[(b << 10) + k]       = to_bf16(x[idx]);
    xcat[(b << 10) + 512 + k] = to_bf16(hx0[idx]);
}

// ---------------- step 0 (K=1024, [x|hx0] @ [Wih|Whh]) ----------------
template <int KLEN>
__global__ __launch_bounds__(256) void lstm_step(
    const unsigned short* __restrict__ A,
    const unsigned short* __restrict__ W,
    const float* __restrict__ bc,
    const float* __restrict__ c_in,
    float* __restrict__ c_out,
    unsigned short* __restrict__ h_out) {
    const int lane = threadIdx.x & 63;
    const int wave = threadIdx.x >> 6;
    const int mn = lane & 15, q = lane >> 4;
    const int rt = blockIdx.x & 15;
    const int hb = (blockIdx.x >> 4) * 64 + wave * 16;

    const unsigned short* ap  = A + (size_t)(rt * 16 + mn) * KLEN + q * 8;
    const unsigned short* wp0 = W + (size_t)(0 * H_ + hb + mn) * KLEN + q * 8;
    const unsigned short* wp1 = W + (size_t)(1 * H_ + hb + mn) * KLEN + q * 8;
    const unsigned short* wp2 = W + (size_t)(2 * H_ + hb + mn) * KLEN + q * 8;
    const unsigned short* wp3 = W + (size_t)(3 * H_ + hb + mn) * KLEN + q * 8;

    f32x4 acc0 = {0.f,0.f,0.f,0.f}, acc1 = {0.f,0.f,0.f,0.f};
    f32x4 acc2 = {0.f,0.f,0.f,0.f}, acc3 = {0.f,0.f,0.f,0.f};
#pragma unroll 4
    for (int k0 = 0; k0 < KLEN; k0 += 32) {
        s16x8 a  = *reinterpret_cast<const s16x8*>(ap + k0);
        s16x8 w0 = *reinterpret_cast<const s16x8*>(wp0 + k0);
        s16x8 w1 = *reinterpret_cast<const s16x8*>(wp1 + k0);
        s16x8 w2 = *reinterpret_cast<const s16x8*>(wp2 + k0);
        s16x8 w3 = *reinterpret_cast<const s16x8*>(wp3 + k0);
        acc0 = __builtin_amdgcn_mfma_f32_16x16x32_bf16(a, w0, acc0, 0, 0, 0);
        acc1 = __builtin_amdgcn_mfma_f32_16x16x32_bf16(a, w1, acc1, 0, 0, 0);
        acc2 = __builtin_amdgcn_mfma_f32_16x16x32_bf16(a, w2, acc2, 0, 0, 0);
        acc3 = __builtin_amdgcn_mfma_f32_16x16x32_bf16(a, w3, acc3, 0, 0, 0);
    }

    const int j = hb + mn;
    const float bi = bc[j], bfv = bc[H_ + j], bg = bc[2 * H_ + j], bo = bc[3 * H_ + j];
#pragma unroll
    for (int r = 0; r < 4; ++r) {
        const int row = rt * 16 + q * 4 + r;
        const float iv = sigmoidf_(acc0[r] + bi);
        const float fv = sigmoidf_(acc1[r] + bfv);
        const float gv = fast_tanh(acc2[r] + bg);
        const float ov = sigmoidf_(acc3[r] + bo);
        const float co = c_in[row * H_ + j];
        const float cn = fv * co + iv * gv;
        c_out[row * H_ + j] = cn;
        h_out[row * H_ + j] = to_bf16(ov * fast_tanh(cn));
    }
}

// ---------------- persistent LSTM (steps 1..325) ----------------
// 256 WGs x 256 thr (cooperative). 8 INDEPENDENT groups: mt = blockIdx&7 owns
// rows [mt*32, mt*32+32); p = blockIdx>>3 owns hidden cols [16p, 16p+16).
// Dataflow sync, LIGHT polling (the R1 lesson: 65536 spinning threads on 32
// cachelines was an L2 storm). Per step each producer publishes a per-producer
// flag (= step id) after its h-store drains. CONSUMER: wave w waits for the 8
// producers of col-quarter w via ONE coalesced 32B load per poll (lanes 0..7
// carry the 8 flags, __all() converges the wave), then bursts its 8KB quarter
// load at full MLP. A WG never waits on its own flag (its stores drained at
// its own __syncthreads). No atomic RMW anywhere on the step path.
// All data ops sc1 (relaxed AGENT atomics) relying on same-XCD L2 (mt =
// blockIdx&7 = XCD id under round-robin dispatch). 3 barriers/step.
__global__ __launch_bounds__(256) void lstm_persist(
    const unsigned short* __restrict__ Wc,   // [2048][512] bf16
    const float* __restrict__ bc,            // [2048]
    const float* __restrict__ c0,            // [256][512] f32 (from step 0)
    unsigned short* __restrict__ h_hist,     // [326][256][512] bf16
    unsigned int* __restrict__ flg) {        // 32 quarter-lines x 128B; 8 flags each
    constexpr int AS = 520;                      // ushort stride (pad 8)
    __shared__ unsigned short A_lds[32 * AS];    // 33280 B
    __shared__ float gate_lds[4 * 32 * 17];      // 8704 B
    const int tid = threadIdx.x;
    const int lane = tid & 63, wave = tid >> 6;
    const int mn = lane & 15, q = lane >> 4;
    const int mt = blockIdx.x & 7;               // group = same XCD
    const int p  = blockIdx.x >> 3;              // col chunk 0..31
    const int jb = p * 16;
    // flag layout: line (mt*4 + quarter) holds flags of its 8 producers
    unsigned int* my_flag = flg + (mt * 4 + (p >> 3)) * 32 + (p & 7);
    // wave `wave` polls+stages col-quarter `wave`; lane&7 indexes its producers
    const unsigned int* poll_addr = flg + (mt * 4 + wave) * 32 + (lane & 7);
    const bool self_flag = (wave == (p >> 3)) && ((lane & 7) == (p & 7));

    // weights -> registers (B-fragment layout: n=mn, k=kk*32+q*8)
    s16x8 breg[16];
    {
        const unsigned short* wp = Wc + (size_t)(wave * H_ + jb + mn) * H_ + q * 8;
#pragma unroll
        for (int kk = 0; kk < 16; ++kk) breg[kk] = *reinterpret_cast<const s16x8*>(wp + kk * 32);
    }
    const float bcv = bc[wave * H_ + jb + mn];

    // owned c/h elements: row = tid>>3 (0..31), cols c0..c0+1 (c0 = 2*(tid&7))
    const int crow = tid >> 3, cc0 = (tid & 7) * 2;
    float c_x = c0[(size_t)(mt * 32 + crow) * H_ + jb + cc0];
    float c_y = c0[(size_t)(mt * 32 + crow) * H_ + jb + cc0 + 1];

    for (int t = 1; t < T_; ++t) {
        // ---- wait for the 8 producers of cols [128*wave, 128*wave+128) ----
        {
            const unsigned int tgt = (unsigned int)(t - 1);
            for (;;) {
                unsigned int f = __hip_atomic_load(poll_addr, __ATOMIC_RELAXED,
                                                   __HIP_MEMORY_SCOPE_AGENT);
                if (self_flag) f = tgt;
                if (__all((int)(f >= tgt))) break;
            }
        }
        asm volatile("" ::: "memory");   // keep data loads after the spin

        // ---- stage quarter `wave`: 32 rows x 128 cols bf16 = 8KB burst ----
        {
            const unsigned long long* hq = reinterpret_cast<const unsigned long long*>(
                h_hist + (size_t)(t - 1) * (B_ * H_) + (size_t)mt * 32 * H_);
            unsigned long long vv[16];
#pragma unroll
            for (int j = 0; j < 16; ++j) {
                const int qi = j * 64 + lane;
                const int row = qi >> 5;          // 32 qwords per quarter-row
                const int qw  = qi & 31;
                vv[j] = __hip_atomic_load(hq + (size_t)row * 128 + wave * 32 + qw,
                                          __ATOMIC_RELAXED, __HIP_MEMORY_SCOPE_AGENT);
            }
#pragma unroll
            for (int j = 0; j < 16; ++j) {
                const int qi = j * 64 + lane;
                const int row = qi >> 5;
                const int qw  = qi & 31;
                *reinterpret_cast<unsigned long long*>(
                    &A_lds[row * AS + wave * 128 + qw * 4]) = vv[j];
            }
        }
        __syncthreads();

        // ---- gates via MFMA (M=32 as 2 subtiles, N=16, K=512) ----
        f32x4 acc0 = {0.f,0.f,0.f,0.f}, acc1 = {0.f,0.f,0.f,0.f};
#pragma unroll
        for (int kk = 0; kk < 16; ++kk) {
            s16x8 a0 = *reinterpret_cast<const s16x8*>(&A_lds[mn * AS + kk * 32 + q * 8]);
            s16x8 a1 = *reinterpret_cast<const s16x8*>(&A_lds[(16 + mn) * AS + kk * 32 + q * 8]);
            acc0 = __builtin_amdgcn_mfma_f32_16x16x32_bf16(a0, breg[kk], acc0, 0, 0, 0);
            acc1 = __builtin_amdgcn_mfma_f32_16x16x32_bf16(a1, breg[kk], acc1, 0, 0, 0);
        }

        // ---- activations -> gate LDS (C-layout: col=mn, row=q*4+r) ----
#pragma unroll
        for (int r = 0; r < 4; ++r) {
            float v0 = acc0[r] + bcv, v1 = acc1[r] + bcv;
            if (wave == 2) { v0 = fast_tanh(v0); v1 = fast_tanh(v1); }
            else           { v0 = sigmoidf_(v0); v1 = sigmoidf_(v1); }
            gate_lds[(wave * 32 + (q * 4 + r)) * 17 + mn]      = v0;
            gate_lds[(wave * 32 + (16 + q * 4 + r)) * 17 + mn] = v1;
        }
        __syncthreads();

        // ---- c/h update (2 adjacent cols of one row per thread) ----
        {
            float iv0 = gate_lds[(0 * 32 + crow) * 17 + cc0], iv1 = gate_lds[(0 * 32 + crow) * 17 + cc0 + 1];
            float fv0 = gate_lds[(1 * 32 + crow) * 17 + cc0], fv1 = gate_lds[(1 * 32 + crow) * 17 + cc0 + 1];
            float gv0 = gate_lds[(2 * 32 + crow) * 17 + cc0], gv1 = gate_lds[(2 * 32 + crow) * 17 + cc0 + 1];
            float ov0 = gate_lds[(3 * 32 + crow) * 17 + cc0], ov1 = gate_lds[(3 * 32 + crow) * 17 + cc0 + 1];
            c_x = fv0 * c_x + iv0 * gv0;
            c_y = fv1 * c_y + iv1 * gv1;
            unsigned int h0 = to_bf16(ov0 * fast_tanh(c_x));
            unsigned int h1 = to_bf16(ov1 * fast_tanh(c_y));
            unsigned int packed = h0 | (h1 << 16);
            unsigned int* hdst = reinterpret_cast<unsigned int*>(
                h_hist + (size_t)t * (B_ * H_) + (size_t)(mt * 32 + crow) * H_ + jb + cc0);
            __hip_atomic_store(hdst, packed, __ATOMIC_RELAXED, __HIP_MEMORY_SCOPE_AGENT);
        }

        // ---- publish: drain h-stores (vmcnt(0) inside __syncthreads), set flag ----
        if (t < T_ - 1) {
            __syncthreads();  // all 256 threads' sc1 h-stores complete in L2
            asm volatile("" ::: "memory");
            if (tid == 0)
                __hip_atomic_store(my_flag, (unsigned int)t, __ATOMIC_RELAXED,
                                   __HIP_MEMORY_SCOPE_AGENT);
        }
    }
}

// ---------------- deferred MLP head ----------------
__global__ __launch_bounds__(256) void mlp_kernel(
    const unsigned short* __restrict__ h_hist,
    const unsigned short* __restrict__ W1b,
    const float* __restrict__ b1,
    const unsigned short* __restrict__ W2b,
    const float* __restrict__ b2,
    float* __restrict__ out) {
    constexpr int ZS = 520;
    __shared__ unsigned short z_lds[32 * ZS];

    const int lane = threadIdx.x & 63;
    const int wave = threadIdx.x >> 6;
    const int mn = lane & 15, q = lane >> 4;
    const int t = blockIdx.x >> 2, mt = blockIdx.x & 3;

    const unsigned short* Abase = h_hist + ((size_t)t * B_ + mt * 64) * H_;
    const int nb = wave * 128;

    f32x4 zero4 = {0.f,0.f,0.f,0.f};
    f32x4 acc[4][8];
#pragma unroll
    for (int m4 = 0; m4 < 4; ++m4)
#pragma unroll
        for (int nt = 0; nt < 8; ++nt) acc[m4][nt] = zero4;

    for (int k0 = 0; k0 < 512; k0 += 32) {
        s16x8 a[4];
#pragma unroll
        for (int m4 = 0; m4 < 4; ++m4)
            a[m4] = *reinterpret_cast<const s16x8*>(Abase + (size_t)(m4 * 16 + mn) * H_ + k0 + q * 8);
#pragma unroll
        for (int nt = 0; nt < 8; ++nt) {
            s16x8 b = *reinterpret_cast<const s16x8*>(W1b + (size_t)(nb + nt * 16 + mn) * H_ + k0 + q * 8);
#pragma unroll
            for (int m4 = 0; m4 < 4; ++m4)
                acc[m4][nt] = __builtin_amdgcn_mfma_f32_16x16x32_bf16(a[m4], b, acc[m4][nt], 0, 0, 0);
        }
    }

    float b1v[8];
#pragma unroll
    for (int nt = 0; nt < 8; ++nt) b1v[nt] = b1[nb + nt * 16 + mn];

    for (int pass = 0; pass < 2; ++pass) {
        __syncthreads();
#pragma unroll
        for (int m4i = 0; m4i < 2; ++m4i) {
            const int m4 = 2 * pass + m4i;
            const int rl = m4i * 16 + q * 4;
#pragma unroll
            for (int nt = 0; nt < 8; ++nt) {
                const int col = nb + nt * 16 + mn;
#pragma unroll
                for (int r = 0; r < 4; ++r) {
                    float v = acc[m4][nt][r] + b1v[nt];
                    v = v > 0.f ? v : 0.f;
                    z_lds[(rl + r) * ZS + col] = to_bf16(v);
                }
            }
        }
        __syncthreads();
        if (wave < 2) {
            f32x4 yacc = {0.f,0.f,0.f,0.f};
#pragma unroll 4
            for (int k0 = 0; k0 < 512; k0 += 32) {
                s16x8 az = *reinterpret_cast<const s16x8*>(&z_lds[(wave * 16 + mn) * ZS + k0 + q * 8]);
                s16x8 bw = *reinterpret_cast<const s16x8*>(W2b + (size_t)mn * H_ + k0 + q * 8);
                yacc = __builtin_amdgcn_mfma_f32_16x16x32_bf16(az, bw, yacc, 0, 0, 0);
            }
            if (mn < OUT_) {
                const float bias = b2[mn];
#pragma unroll
                for (int r = 0; r < 4; ++r) {
                    const int row_local = pass * 32 + wave * 16 + q * 4 + r;
                    const int b = mt * 64 + row_local;
                    out[(size_t)b * (T_ * OUT_) + t * OUT_ + mn] = yacc[r] + bias;
                }
            }
        }
    }
}

// ---------------- host launch ----------------
extern "C" void kernel_launch(void* const* d_in, const int* in_sizes, int n_in,
                              void* d_out, int out_size, void* d_ws, size_t ws_size,
                              hipStream_t stream) {
    (void)in_sizes; (void)n_in; (void)out_size;
    const float* x   = (const float*)d_in[0];
    const float* hx0 = (const float*)d_in[1];
    const float* cx0 = (const float*)d_in[2];
    const float* Wih = (const float*)d_in[3];
    const float* Whh = (const float*)d_in[4];
    const float* bih = (const float*)d_in[5];
    const float* bhh = (const float*)d_in[6];
    const float* W1  = (const float*)d_in[7];
    const float* b1  = (const float*)d_in[8];
    const float* W2  = (const float*)d_in[9];
    const float* b2  = (const float*)d_in[10];
    float* out = (float*)d_out;

    char* p = (char*)d_ws;
    size_t off = 0;
    auto alloc = [&](size_t bytes) {
        void* r = p + off;
        off = (off + bytes + 255) & ~(size_t)255;
        return r;
    };
    unsigned short* Wc     = (unsigned short*)alloc((size_t)G4_ * H_ * 2);
    unsigned short* Wcat   = (unsigned short*)alloc((size_t)G4_ * 1024 * 2);
    unsigned short* W1b    = (unsigned short*)alloc((size_t)H_ * H_ * 2);
    unsigned short* W2b    = (unsigned short*)alloc((size_t)16 * H_ * 2);
    float*          bc     = (float*)alloc((size_t)G4_ * 4);
    unsigned short* xcat   = (unsigned short*)alloc((size_t)B_ * 1024 * 2);
    float*          cbuf   = (float*)alloc((size_t)B_ * H_ * 4);
    unsigned int*   flg    = (unsigned int*)alloc(4096);
    unsigned short* h_hist = (unsigned short*)alloc((size_t)T_ * B_ * H_ * 2);
    if (off > ws_size) {
        fprintf(stderr, "kernel_launch: ws too small: need %zu have %zu\n", off, ws_size);
        return;
    }

    prep_weights<<<G4_ * H_ / 256, 256, 0, stream>>>(Wih, Whh, bih, bhh, Wc, Wcat, bc);
    prep_w1<<<H_ * H_ / 256, 256, 0, stream>>>(W1, W1b);
    prep_w2<<<16 * H_ / 256, 256, 0, stream>>>(W2, W2b);
    prep_x<<<B_ * H_ / 256, 256, 0, stream>>>(x, hx0, xcat);

    // step 0: K=1024
    lstm_step<1024><<<128, 256, 0, stream>>>(xcat, Wcat, bc, cx0, cbuf, h_hist);

    // zero producer flags (flag==0 means "step 0 ready"), then persistent steps 1..325
    hipMemsetAsync(flg, 0, 4096, stream);
    {
        const unsigned short* Wc_l = Wc;
        const float* bc_l = bc;
        const float* c0_l = cbuf;
        unsigned short* hh_l = h_hist;
        unsigned int* flg_l = flg;
        void* args[5] = {(void*)&Wc_l, (void*)&bc_l, (void*)&c0_l, (void*)&hh_l, (void*)&flg_l};
        hipLaunchCooperativeKernel((const void*)lstm_persist, dim3(256), dim3(256), args, 0, stream);
    }

    mlp_kernel<<<T_ * 4, 256, 0, stream>>>(h_hist, W1b, b1, W2b, b2, out);
}

// Round 3
// 1018.988 us; speedup vs baseline: 1.7741x; 1.4936x over previous
//
#include <hip/hip_runtime.h>
#include <cstdio>

#define B_   256
#define H_   512
#define G4_  2048
#define T_   326
#define OUT_ 9

typedef __attribute__((ext_vector_type(8))) short s16x8;
typedef __attribute__((ext_vector_type(4))) float f32x4;

__device__ inline unsigned short to_bf16(float f) {
    unsigned int u = __builtin_bit_cast(unsigned int, f);
    unsigned int r = (u + 0x7fffu + ((u >> 16) & 1u)) >> 16;  // RNE
    return (unsigned short)r;
}

__device__ inline float sigmoidf_(float x) { return 1.0f / (1.0f + __expf(-x)); }

__device__ inline float fast_tanh(float x) {
    x = fminf(fmaxf(x, -15.f), 15.f);
    float e = __expf(2.f * x);
    return (e - 1.f) / (e + 1.f);
}

// ---------------- prep kernels ----------------

__global__ void prep_weights(const float* __restrict__ Wih, const float* __restrict__ Whh,
                             const float* __restrict__ bih, const float* __restrict__ bhh,
                             unsigned short* __restrict__ Wc, unsigned short* __restrict__ Wcat,
                             float* __restrict__ bc) {
    int idx = blockIdx.x * 256 + threadIdx.x;      // < 2048*512
    int n = idx >> 9, k = idx & 511;
    float wi = Wih[idx], wh = Whh[idx];
    Wc[idx] = to_bf16(wi + wh);
    Wcat[(n << 10) + k]       = to_bf16(wi);
    Wcat[(n << 10) + 512 + k] = to_bf16(wh);
    if (k == 0) bc[n] = bih[n] + bhh[n];
}

__global__ void prep_w1(const float* __restrict__ W1, unsigned short* __restrict__ W1b) {
    int idx = blockIdx.x * 256 + threadIdx.x;      // < 512*512
    W1b[idx] = to_bf16(W1[idx]);
}

__global__ void prep_w2(const float* __restrict__ W2, unsigned short* __restrict__ W2b) {
    int idx = blockIdx.x * 256 + threadIdx.x;      // < 16*512
    int o = idx >> 9, k = idx & 511;
    W2b[idx] = (o < OUT_) ? to_bf16(W2[o * H_ + k]) : (unsigned short)0;
}

__global__ void prep_x(const float* __restrict__ x, const float* __restrict__ hx0,
                       unsigned short* __restrict__ xcat) {
    int idx = blockIdx.x * 256 + threadIdx.x;      // < 256*512
    int b = idx >> 9, k = idx & 511;
    xcat[(b << 10) + k]       = to_bf16(x[idx]);
    xcat[(b << 10) + 512 + k] = to_bf16(hx0[idx]);
}

// ---------------- step 0 (K=1024, [x|hx0] @ [Wih|Whh]) ----------------
template <int KLEN>
__global__ __launch_bounds__(256) void lstm_step(
    const unsigned short* __restrict__ A,
    const unsigned short* __restrict__ W,
    const float* __restrict__ bc,
    const float* __restrict__ c_in,
    float* __restrict__ c_out,
    unsigned short* __restrict__ h_out) {
    const int lane = threadIdx.x & 63;
    const int wave = threadIdx.x >> 6;
    const int mn = lane & 15, q = lane >> 4;
    const int rt = blockIdx.x & 15;
    const int hb = (blockIdx.x >> 4) * 64 + wave * 16;

    const unsigned short* ap  = A + (size_t)(rt * 16 + mn) * KLEN + q * 8;
    const unsigned short* wp0 = W + (size_t)(0 * H_ + hb + mn) * KLEN + q * 8;
    const unsigned short* wp1 = W + (size_t)(1 * H_ + hb + mn) * KLEN + q * 8;
    const unsigned short* wp2 = W + (size_t)(2 * H_ + hb + mn) * KLEN + q * 8;
    const unsigned short* wp3 = W + (size_t)(3 * H_ + hb + mn) * KLEN + q * 8;

    f32x4 acc0 = {0.f,0.f,0.f,0.f}, acc1 = {0.f,0.f,0.f,0.f};
    f32x4 acc2 = {0.f,0.f,0.f,0.f}, acc3 = {0.f,0.f,0.f,0.f};
#pragma unroll 4
    for (int k0 = 0; k0 < KLEN; k0 += 32) {
        s16x8 a  = *reinterpret_cast<const s16x8*>(ap + k0);
        s16x8 w0 = *reinterpret_cast<const s16x8*>(wp0 + k0);
        s16x8 w1 = *reinterpret_cast<const s16x8*>(wp1 + k0);
        s16x8 w2 = *reinterpret_cast<const s16x8*>(wp2 + k0);
        s16x8 w3 = *reinterpret_cast<const s16x8*>(wp3 + k0);
        acc0 = __builtin_amdgcn_mfma_f32_16x16x32_bf16(a, w0, acc0, 0, 0, 0);
        acc1 = __builtin_amdgcn_mfma_f32_16x16x32_bf16(a, w1, acc1, 0, 0, 0);
        acc2 = __builtin_amdgcn_mfma_f32_16x16x32_bf16(a, w2, acc2, 0, 0, 0);
        acc3 = __builtin_amdgcn_mfma_f32_16x16x32_bf16(a, w3, acc3, 0, 0, 0);
    }

    const int j = hb + mn;
    const float bi = bc[j], bfv = bc[H_ + j], bg = bc[2 * H_ + j], bo = bc[3 * H_ + j];
#pragma unroll
    for (int r = 0; r < 4; ++r) {
        const int row = rt * 16 + q * 4 + r;
        const float iv = sigmoidf_(acc0[r] + bi);
        const float fv = sigmoidf_(acc1[r] + bfv);
        const float gv = fast_tanh(acc2[r] + bg);
        const float ov = sigmoidf_(acc3[r] + bo);
        const float co = c_in[row * H_ + j];
        const float cn = fv * co + iv * gv;
        c_out[row * H_ + j] = cn;
        h_out[row * H_ + j] = to_bf16(ov * fast_tanh(cn));
    }
}

// ---------------- persistent LSTM (steps 1..325) ----------------
// R0 mechanics (counter barrier, tid0 spinner, parked waves), re-partitioned:
// 16 INDEPENDENT groups of 16 batch-rows. g = blockIdx&15 (=> fixed XCD since
// blockIdx%8 = g%8); 16 WGs per group, each owning 32 hidden cols
// (jb = (blockIdx>>4)*32). Halves: barrier participants (16 RMWs), straggler
// pool, per-XCD L2 read burst (512KB/step), A-staging (8 loads/thread).
// Same compute per WG as R0 (M=16 exactly one MFMA tile, N=2x16 per wave).
// A_lds uses XOR-16B swizzle on BOTH write and read sides (manual staging) to
// kill the 4-8 way ds_read_b128 bank conflict R0 measured (5.3e7 cycles).
__global__ __launch_bounds__(256) void lstm_persist(
    const unsigned short* __restrict__ Wc,   // [2048][512] bf16
    const float* __restrict__ bc,            // [2048]
    const float* __restrict__ c0,            // [256][512] f32 (from step 0)
    unsigned short* __restrict__ h_hist,     // [326][256][512] bf16
    unsigned int* __restrict__ ctr) {        // 16 counters, 128B apart
    __shared__ unsigned short A_lds[16 * 512];   // 16 KB, swizzled
    __shared__ float gate_lds[4 * 16 * 33];      // 8448 B
    const int tid = threadIdx.x;
    const int lane = tid & 63, wave = tid >> 6;
    const int mn = lane & 15, q = lane >> 4;
    const int g  = blockIdx.x & 15;              // group (same XCD: g%8)
    const int jb = (blockIdx.x >> 4) * 32;       // 32 cols per WG
    unsigned int* ctr_g = ctr + g * 32;          // own cacheline per group

    // weights -> registers: wave = gate, two 16-col N-tiles
    s16x8 breg[2][16];
#pragma unroll
    for (int n = 0; n < 2; ++n) {
        const unsigned short* wp = Wc + (size_t)(wave * H_ + jb + n * 16 + mn) * H_ + q * 8;
#pragma unroll
        for (int kk = 0; kk < 16; ++kk)
            breg[n][kk] = *reinterpret_cast<const s16x8*>(wp + kk * 32);
    }
    const float bcv0 = bc[wave * H_ + jb + mn];
    const float bcv1 = bc[wave * H_ + jb + 16 + mn];

    // owned c/h: row crow (0..15), adjacent cols cc0..cc0+1
    const int crow = tid >> 4, cc0 = (tid & 15) * 2;
    float c_x = c0[(size_t)(g * 16 + crow) * H_ + jb + cc0];
    float c_y = c0[(size_t)(g * 16 + crow) * H_ + jb + cc0 + 1];

    // precomputed swizzled ushort indices for A staging (8 qwords/thread)
    int a_st[8];
#pragma unroll
    for (int p = 0; p < 8; ++p) {
        const int qi = p * 256 + tid;
        const int row = qi >> 7;                 // 128 qwords per 512-col row
        const int bcol = (qi & 127) * 8;         // byte col within row
        a_st[p] = row * 512 + (((bcol) ^ ((row & 7) << 4)) >> 1);
    }
    // precomputed swizzled ushort indices for A reads (row = mn)
    int a_rd[16];
#pragma unroll
    for (int kk = 0; kk < 16; ++kk) {
        const int bcol = kk * 64 + q * 16;
        a_rd[kk] = mn * 512 + ((bcol ^ ((mn & 7) << 4)) >> 1);
    }

    for (int t = 1; t < T_; ++t) {
        // ---- stage A = h_{t-1} rows [g*16, g*16+16) via sc1 8B loads ----
        const unsigned long long* hsrc64 = reinterpret_cast<const unsigned long long*>(
            h_hist + (size_t)(t - 1) * (B_ * H_) + (size_t)g * 16 * H_);
        unsigned long long vv[8];
#pragma unroll
        for (int p = 0; p < 8; ++p)
            vv[p] = __hip_atomic_load(hsrc64 + p * 256 + tid, __ATOMIC_RELAXED,
                                      __HIP_MEMORY_SCOPE_AGENT);
#pragma unroll
        for (int p = 0; p < 8; ++p)
            *reinterpret_cast<unsigned long long*>(&A_lds[a_st[p]]) = vv[p];
        __syncthreads();

        // ---- gates via MFMA (M=16, N=2x16, K=512) ----
        f32x4 acc0 = {0.f,0.f,0.f,0.f}, acc1 = {0.f,0.f,0.f,0.f};
#pragma unroll
        for (int kk = 0; kk < 16; ++kk) {
            s16x8 a = *reinterpret_cast<const s16x8*>(&A_lds[a_rd[kk]]);
            acc0 = __builtin_amdgcn_mfma_f32_16x16x32_bf16(a, breg[0][kk], acc0, 0, 0, 0);
            acc1 = __builtin_amdgcn_mfma_f32_16x16x32_bf16(a, breg[1][kk], acc1, 0, 0, 0);
        }

        // ---- activations -> gate LDS (row=q*4+r, cols mn / 16+mn) ----
#pragma unroll
        for (int r = 0; r < 4; ++r) {
            float v0 = acc0[r] + bcv0, v1 = acc1[r] + bcv1;
            if (wave == 2) { v0 = fast_tanh(v0); v1 = fast_tanh(v1); }
            else           { v0 = sigmoidf_(v0); v1 = sigmoidf_(v1); }
            gate_lds[(wave * 16 + (q * 4 + r)) * 33 + mn]      = v0;
            gate_lds[(wave * 16 + (q * 4 + r)) * 33 + 16 + mn] = v1;
        }
        __syncthreads();

        // ---- c/h update (2 adjacent cols of one row per thread) ----
        {
            float iv0 = gate_lds[(0 * 16 + crow) * 33 + cc0], iv1 = gate_lds[(0 * 16 + crow) * 33 + cc0 + 1];
            float fv0 = gate_lds[(1 * 16 + crow) * 33 + cc0], fv1 = gate_lds[(1 * 16 + crow) * 33 + cc0 + 1];
            float gv0 = gate_lds[(2 * 16 + crow) * 33 + cc0], gv1 = gate_lds[(2 * 16 + crow) * 33 + cc0 + 1];
            float ov0 = gate_lds[(3 * 16 + crow) * 33 + cc0], ov1 = gate_lds[(3 * 16 + crow) * 33 + cc0 + 1];
            c_x = fv0 * c_x + iv0 * gv0;
            c_y = fv1 * c_y + iv1 * gv1;
            unsigned int h0 = to_bf16(ov0 * fast_tanh(c_x));
            unsigned int h1 = to_bf16(ov1 * fast_tanh(c_y));
            unsigned int packed = h0 | (h1 << 16);
            unsigned int* hdst = reinterpret_cast<unsigned int*>(
                h_hist + (size_t)t * (B_ * H_) + (size_t)(g * 16 + crow) * H_ + jb + cc0);
            __hip_atomic_store(hdst, packed, __ATOMIC_RELAXED, __HIP_MEMORY_SCOPE_AGENT);
        }

        // ---- per-group barrier (16 WGs), R0 mechanics ----
        if (t < T_ - 1) {
            __syncthreads();  // emits s_waitcnt vmcnt(0): sc1 h-stores complete
            asm volatile("" ::: "memory");
            if (tid == 0) {
                __hip_atomic_fetch_add(ctr_g, 1u, __ATOMIC_RELAXED, __HIP_MEMORY_SCOPE_AGENT);
                const unsigned int target = 16u * (unsigned int)t;
                while (__hip_atomic_load(ctr_g, __ATOMIC_RELAXED, __HIP_MEMORY_SCOPE_AGENT) < target) {
                }
            }
            asm volatile("" ::: "memory");
            __syncthreads();
        }
    }
}

// ---------------- deferred MLP head ----------------
__global__ __launch_bounds__(256) void mlp_kernel(
    const unsigned short* __restrict__ h_hist,
    const unsigned short* __restrict__ W1b,
    const float* __restrict__ b1,
    const unsigned short* __restrict__ W2b,
    const float* __restrict__ b2,
    float* __restrict__ out) {
    constexpr int ZS = 520;
    __shared__ unsigned short z_lds[32 * ZS];

    const int lane = threadIdx.x & 63;
    const int wave = threadIdx.x >> 6;
    const int mn = lane & 15, q = lane >> 4;
    const int t = blockIdx.x >> 2, mt = blockIdx.x & 3;

    const unsigned short* Abase = h_hist + ((size_t)t * B_ + mt * 64) * H_;
    const int nb = wave * 128;

    f32x4 zero4 = {0.f,0.f,0.f,0.f};
    f32x4 acc[4][8];
#pragma unroll
    for (int m4 = 0; m4 < 4; ++m4)
#pragma unroll
        for (int nt = 0; nt < 8; ++nt) acc[m4][nt] = zero4;

    for (int k0 = 0; k0 < 512; k0 += 32) {
        s16x8 a[4];
#pragma unroll
        for (int m4 = 0; m4 < 4; ++m4)
            a[m4] = *reinterpret_cast<const s16x8*>(Abase + (size_t)(m4 * 16 + mn) * H_ + k0 + q * 8);
#pragma unroll
        for (int nt = 0; nt < 8; ++nt) {
            s16x8 b = *reinterpret_cast<const s16x8*>(W1b + (size_t)(nb + nt * 16 + mn) * H_ + k0 + q * 8);
#pragma unroll
            for (int m4 = 0; m4 < 4; ++m4)
                acc[m4][nt] = __builtin_amdgcn_mfma_f32_16x16x32_bf16(a[m4], b, acc[m4][nt], 0, 0, 0);
        }
    }

    float b1v[8];
#pragma unroll
    for (int nt = 0; nt < 8; ++nt) b1v[nt] = b1[nb + nt * 16 + mn];

    for (int pass = 0; pass < 2; ++pass) {
        __syncthreads();
#pragma unroll
        for (int m4i = 0; m4i < 2; ++m4i) {
            const int m4 = 2 * pass + m4i;
            const int rl = m4i * 16 + q * 4;
#pragma unroll
            for (int nt = 0; nt < 8; ++nt) {
                const int col = nb + nt * 16 + mn;
#pragma unroll
                for (int r = 0; r < 4; ++r) {
                    float v = acc[m4][nt][r] + b1v[nt];
                    v = v > 0.f ? v : 0.f;
                    z_lds[(rl + r) * ZS + col] = to_bf16(v);
                }
            }
        }
        __syncthreads();
        if (wave < 2) {
            f32x4 yacc = {0.f,0.f,0.f,0.f};
#pragma unroll 4
            for (int k0 = 0; k0 < 512; k0 += 32) {
                s16x8 az = *reinterpret_cast<const s16x8*>(&z_lds[(wave * 16 + mn) * ZS + k0 + q * 8]);
                s16x8 bw = *reinterpret_cast<const s16x8*>(W2b + (size_t)mn * H_ + k0 + q * 8);
                yacc = __builtin_amdgcn_mfma_f32_16x16x32_bf16(az, bw, yacc, 0, 0, 0);
            }
            if (mn < OUT_) {
                const float bias = b2[mn];
#pragma unroll
                for (int r = 0; r < 4; ++r) {
                    const int row_local = pass * 32 + wave * 16 + q * 4 + r;
                    const int b = mt * 64 + row_local;
                    out[(size_t)b * (T_ * OUT_) + t * OUT_ + mn] = yacc[r] + bias;
                }
            }
        }
    }
}

// ---------------- host launch ----------------
extern "C" void kernel_launch(void* const* d_in, const int* in_sizes, int n_in,
                              void* d_out, int out_size, void* d_ws, size_t ws_size,
                              hipStream_t stream) {
    (void)in_sizes; (void)n_in; (void)out_size;
    const float* x   = (const float*)d_in[0];
    const float* hx0 = (const float*)d_in[1];
    const float* cx0 = (const float*)d_in[2];
    const float* Wih = (const float*)d_in[3];
    const float* Whh = (const float*)d_in[4];
    const float* bih = (const float*)d_in[5];
    const float* bhh = (const float*)d_in[6];
    const float* W1  = (const float*)d_in[7];
    const float* b1  = (const float*)d_in[8];
    const float* W2  = (const float*)d_in[9];
    const float* b2  = (const float*)d_in[10];
    float* out = (float*)d_out;

    char* p = (char*)d_ws;
    size_t off = 0;
    auto alloc = [&](size_t bytes) {
        void* r = p + off;
        off = (off + bytes + 255) & ~(size_t)255;
        return r;
    };
    unsigned short* Wc     = (unsigned short*)alloc((size_t)G4_ * H_ * 2);
    unsigned short* Wcat   = (unsigned short*)alloc((size_t)G4_ * 1024 * 2);
    unsigned short* W1b    = (unsigned short*)alloc((size_t)H_ * H_ * 2);
    unsigned short* W2b    = (unsigned short*)alloc((size_t)16 * H_ * 2);
    float*          bc     = (float*)alloc((size_t)G4_ * 4);
    unsigned short* xcat   = (unsigned short*)alloc((size_t)B_ * 1024 * 2);
    float*          cbuf   = (float*)alloc((size_t)B_ * H_ * 4);
    unsigned int*   ctr    = (unsigned int*)alloc(4096);
    unsigned short* h_hist = (unsigned short*)alloc((size_t)T_ * B_ * H_ * 2);
    if (off > ws_size) {
        fprintf(stderr, "kernel_launch: ws too small: need %zu have %zu\n", off, ws_size);
        return;
    }

    prep_weights<<<G4_ * H_ / 256, 256, 0, stream>>>(Wih, Whh, bih, bhh, Wc, Wcat, bc);
    prep_w1<<<H_ * H_ / 256, 256, 0, stream>>>(W1, W1b);
    prep_w2<<<16 * H_ / 256, 256, 0, stream>>>(W2, W2b);
    prep_x<<<B_ * H_ / 256, 256, 0, stream>>>(x, hx0, xcat);

    // step 0: K=1024
    lstm_step<1024><<<128, 256, 0, stream>>>(xcat, Wcat, bc, cx0, cbuf, h_hist);

    // zero group counters, then persistent steps 1..325
    hipMemsetAsync(ctr, 0, 4096, stream);
    {
        const unsigned short* Wc_l = Wc;
        const float* bc_l = bc;
        const float* c0_l = cbuf;
        unsigned short* hh_l = h_hist;
        unsigned int* ctr_l = ctr;
        void* args[5] = {(void*)&Wc_l, (void*)&bc_l, (void*)&c0_l, (void*)&hh_l, (void*)&ctr_l};
        hipLaunchCooperativeKernel((const void*)lstm_persist, dim3(256), dim3(256), args, 0, stream);
    }

    mlp_kernel<<<T_ * 4, 256, 0, stream>>>(h_hist, W1b, b1, W2b, b2, out);
}